// Round 4
// baseline (263.462 us; speedup 1.0000x reference)
//
#include <hip/hip_runtime.h>

#define D_MODEL 768
#define D_STATE 16
#define D_INNER 1536
#define DT_RANK 48
#define NB 2
#define LSEQ 1024
#define NROWS (NB * LSEQ)
#define CCH 16                 // chunks over L
#define CLEN (LSEQ / CCH)      // 64 steps per chunk
#define STP 16                 // steps staged per LDS tile
#define BETA_CL 1.1790185e-03f // 0.9^64

typedef __attribute__((ext_vector_type(4))) float f32x4;
typedef __attribute__((ext_vector_type(8))) short s16x8;
typedef __attribute__((ext_vector_type(8))) unsigned short u16x8;
typedef __attribute__((ext_vector_type(4))) unsigned short u16x4;

__device__ __forceinline__ unsigned short f2bu(float f) {
  unsigned int x = __builtin_bit_cast(unsigned int, f);
  x += 0x7fffu + ((x >> 16) & 1u);
  return (unsigned short)(x >> 16);
}

// direct global->LDS async copy, 16B per lane. LDS dest is wave-uniform base +
// lane*16 (m104): pass the wave's segment base, lanes are implicit.
typedef __attribute__((address_space(3))) unsigned int as3u32;
typedef __attribute__((address_space(1))) const unsigned int as1u32;
__device__ __forceinline__ void gload16(const unsigned short* g, unsigned short* l) {
  __builtin_amdgcn_global_load_lds((as1u32*)g, (as3u32*)l, 16, 0, 0);
}

// ---- one-shot: cvt 5 static operands to bf16 + zero split-K atomic targets ----
// cvt segments (8-elem groups): hidden 196608 | w_in 294912 | w_x 15360 | w_dt 9216 | w_out 147456
#define CVT_TOTAL 663552
#define Z1_GROUPS 20480   // xdbl: 163840 floats
#define Z2_GROUPS 196608  // d_out: 1572864 floats
#define Z3_GROUPS 786432  // xz: 6291456 floats (in_proj split-K atomic target)
__global__ __launch_bounds__(256) void cvt5z_kernel(const float* __restrict__ s0,
                                                    const float* __restrict__ s1,
                                                    const float* __restrict__ s2,
                                                    const float* __restrict__ s3,
                                                    const float* __restrict__ s4,
                                                    unsigned short* __restrict__ d0,
                                                    unsigned short* __restrict__ d1,
                                                    unsigned short* __restrict__ d2,
                                                    unsigned short* __restrict__ d3,
                                                    unsigned short* __restrict__ d4,
                                                    float* __restrict__ z1,
                                                    float* __restrict__ z2,
                                                    float* __restrict__ z3) {
  int g = blockIdx.x * 256 + threadIdx.x;
  if (g >= CVT_TOTAL) {
    int zg = g - CVT_TOTAL;
    f32x4 zero = {0.f, 0.f, 0.f, 0.f};
    if (zg < Z1_GROUPS) {
      *(f32x4*)(z1 + zg * 8) = zero;
      *(f32x4*)(z1 + zg * 8 + 4) = zero;
    } else if (zg < Z1_GROUPS + Z2_GROUPS) {
      int i = (zg - Z1_GROUPS) * 8;
      *(f32x4*)(z2 + i) = zero;
      *(f32x4*)(z2 + i + 4) = zero;
    } else {
      int i = (zg - Z1_GROUPS - Z2_GROUPS) * 8;
      *(f32x4*)(z3 + i) = zero;
      *(f32x4*)(z3 + i + 4) = zero;
    }
    return;
  }
  const float* s;
  unsigned short* d;
  int base;
  if (g < 196608)      { s = s0; d = d0; base = 0; }
  else if (g < 491520) { s = s1; d = d1; base = 196608; }
  else if (g < 506880) { s = s2; d = d2; base = 491520; }
  else if (g < 516096) { s = s3; d = d3; base = 506880; }
  else                 { s = s4; d = d4; base = 516096; }
  int i = (g - base) * 8;
  f32x4 a = *(const f32x4*)(s + i);
  f32x4 b = *(const f32x4*)(s + i + 4);
  u16x8 o;
#pragma unroll
  for (int j = 0; j < 4; j++) { o[j] = f2bu(a[j]); o[4 + j] = f2bu(b[j]); }
  *(u16x8*)(d + i) = o;
}

// ---- 128x128 GEMM, bf16 in, fp32 accum. REQUIRES M%128==0, N%128==0, kseg%32==0 ----
// 4 waves, each 64x64 (4x4 16x16 frags, 16 MFMA / K32-iter). Double-buffered LDS,
// staged via global_load_lds dwordx4 (m97 structure: linear [128][32], no pad).
template <bool ATOMIC>
__global__ __launch_bounds__(256) void gemm128(const unsigned short* __restrict__ A,
                                               const unsigned short* __restrict__ B,
                                               float* __restrict__ C, int K,
                                               int lda, int ldb, int ldc, int kseg_len) {
  __shared__ __align__(16) unsigned short As[2][128 * 32];
  __shared__ __align__(16) unsigned short Bs[2][128 * 32];
  const int m0 = blockIdx.y * 128, n0 = blockIdx.x * 128;
  const int kbeg = blockIdx.z * kseg_len;
  const int kend = kbeg + kseg_len;
  const int t = threadIdx.x;
  const int wave = t >> 6, lane = t & 63;
  const int wm = wave >> 1, wn = wave & 1;
  const int quad = lane >> 4, l16 = lane & 15;
  const int srow = lane >> 2;       // row within a 16-row wave segment
  const int kcol = (lane & 3) * 8;  // bf16 elems within the 32-wide K slab

  auto stage = [&](int bi, int k0) {
#pragma unroll
    for (int r = 0; r < 2; r++) {
      const int seg = r * 64 + wave * 16;
      gload16(A + (size_t)(m0 + seg + srow) * lda + k0 + kcol, &As[bi][seg * 32]);
      gload16(B + (size_t)(n0 + seg + srow) * ldb + k0 + kcol, &Bs[bi][seg * 32]);
    }
  };

  f32x4 acc[4][4] = {};
  stage(0, kbeg);
  __syncthreads();
  int buf = 0;
  for (int k0 = kbeg; k0 < kend; k0 += 32) {
    if (k0 + 32 < kend) stage(buf ^ 1, k0 + 32);  // loads in flight during MFMA
    s16x8 af[4], bf[4];
#pragma unroll
    for (int i = 0; i < 4; i++) {
      af[i] = *(const s16x8*)&As[buf][(wm * 64 + i * 16 + l16) * 32 + quad * 8];
      bf[i] = *(const s16x8*)&Bs[buf][(wn * 64 + i * 16 + l16) * 32 + quad * 8];
    }
#pragma unroll
    for (int mi = 0; mi < 4; mi++)
#pragma unroll
      for (int ni = 0; ni < 4; ni++)
        acc[mi][ni] = __builtin_amdgcn_mfma_f32_16x16x32_bf16(af[mi], bf[ni], acc[mi][ni], 0, 0, 0);
    __syncthreads();
    buf ^= 1;
  }
#pragma unroll
  for (int mi = 0; mi < 4; mi++)
#pragma unroll
    for (int ni = 0; ni < 4; ni++)
#pragma unroll
      for (int r = 0; r < 4; r++) {
        int row = m0 + wm * 64 + mi * 16 + quad * 4 + r;
        int col = n0 + wn * 64 + ni * 16 + l16;
        if constexpr (ATOMIC)
          atomicAdd(&C[(size_t)row * ldc + col], acc[mi][ni][r]);
        else
          C[(size_t)row * ldc + col] = acc[mi][ni][r];
      }
}

// ---- 64x64 GEMM (bounds-checked) for x_proj / dt_head ----
template <bool AF32, bool ATOMIC>
__global__ __launch_bounds__(256) void gemm_bt(const void* __restrict__ Av,
                                               const unsigned short* __restrict__ B,
                                               float* __restrict__ C, int M, int N, int K,
                                               int lda, int ldb, int ldc, int kseg_len) {
  __shared__ __align__(16) unsigned short As[2][64][40];
  __shared__ __align__(16) unsigned short Bs[2][64][40];
  const int m0 = blockIdx.y * 64, n0 = blockIdx.x * 64;
  const int kbeg = blockIdx.z * kseg_len;
  const int kend = (kbeg + kseg_len < K) ? (kbeg + kseg_len) : K;
  const int t = threadIdx.x;
  const int wave = t >> 6, lane = t & 63;
  const int wm = wave >> 1, wn = wave & 1;
  const int quad = lane >> 4, l16 = lane & 15;
  const int srow = t >> 2;
  const int kseg = (t & 3) * 8;
  const bool va = (m0 + srow) < M, vb = (n0 + srow) < N;
  const float* Af = (const float*)Av;
  const unsigned short* Ab = (const unsigned short*)Av;
  const unsigned short* Bp = B + (size_t)(n0 + srow) * ldb;

  f32x4 ra0, ra1;
  u16x8 rab, rbb;
  auto pref = [&](int k0) {
    const int kk = k0 + kseg;
    const int krem = kend - kk;
    if constexpr (AF32) {
      const float* Ap = Af + (size_t)(m0 + srow) * lda + kk;
      if (va && krem >= 8) {
        ra0 = *(const f32x4*)Ap;
        ra1 = *(const f32x4*)(Ap + 4);
      } else {
#pragma unroll
        for (int j = 0; j < 4; j++) {
          ra0[j] = (va && j < krem) ? Ap[j] : 0.0f;
          ra1[j] = (va && j + 4 < krem) ? Ap[j + 4] : 0.0f;
        }
      }
    } else {
      const unsigned short* Ap = Ab + (size_t)(m0 + srow) * lda + kk;
      if (va && krem >= 8) {
        rab = *(const u16x8*)Ap;
      } else {
#pragma unroll
        for (int j = 0; j < 8; j++) rab[j] = (va && j < krem) ? Ap[j] : (unsigned short)0;
      }
    }
    if (vb && krem >= 8) {
      rbb = *(const u16x8*)(Bp + kk);
    } else {
#pragma unroll
      for (int j = 0; j < 8; j++) rbb[j] = (vb && j < krem) ? Bp[kk + j] : (unsigned short)0;
    }
  };
  auto tolds = [&](int bi) {
    if constexpr (AF32) {
      u16x8 oa;
#pragma unroll
      for (int j = 0; j < 4; j++) { oa[j] = f2bu(ra0[j]); oa[4 + j] = f2bu(ra1[j]); }
      *(u16x8*)&As[bi][srow][kseg] = oa;
    } else {
      *(u16x8*)&As[bi][srow][kseg] = rab;
    }
    *(u16x8*)&Bs[bi][srow][kseg] = rbb;
  };

  f32x4 acc[2][2] = {};
  pref(kbeg);
  tolds(0);
  __syncthreads();
  int buf = 0;
  for (int k0 = kbeg; k0 < kend; k0 += 32) {
    const bool more = (k0 + 32 < kend);
    if (more) pref(k0 + 32);
    s16x8 a0 = *(const s16x8*)&As[buf][wm * 32 + l16][quad * 8];
    s16x8 a1 = *(const s16x8*)&As[buf][wm * 32 + 16 + l16][quad * 8];
    s16x8 b0 = *(const s16x8*)&Bs[buf][wn * 32 + l16][quad * 8];
    s16x8 b1 = *(const s16x8*)&Bs[buf][wn * 32 + 16 + l16][quad * 8];
    acc[0][0] = __builtin_amdgcn_mfma_f32_16x16x32_bf16(a0, b0, acc[0][0], 0, 0, 0);
    acc[0][1] = __builtin_amdgcn_mfma_f32_16x16x32_bf16(a0, b1, acc[0][1], 0, 0, 0);
    acc[1][0] = __builtin_amdgcn_mfma_f32_16x16x32_bf16(a1, b0, acc[1][0], 0, 0, 0);
    acc[1][1] = __builtin_amdgcn_mfma_f32_16x16x32_bf16(a1, b1, acc[1][1], 0, 0, 0);
    if (more) tolds(buf ^ 1);
    __syncthreads();
    buf ^= 1;
  }
#pragma unroll
  for (int mi = 0; mi < 2; mi++)
#pragma unroll
    for (int ni = 0; ni < 2; ni++)
#pragma unroll
      for (int r = 0; r < 4; r++) {
        int row = m0 + wm * 32 + mi * 16 + quad * 4 + r;
        int col = n0 + wn * 32 + ni * 16 + l16;
        if (row < M && col < N) {
          if constexpr (ATOMIC)
            atomicAdd(&C[(size_t)row * ldc + col], acc[mi][ni][r]);
          else
            C[(size_t)row * ldc + col] = acc[mi][ni][r];
        }
      }
}

// ---- causal depthwise conv (width 4) + SiLU; 4 channels/thread, 16B loads ----
__global__ __launch_bounds__(256) void conv_silu_kernel(const float* __restrict__ xz,
                                                        const float* __restrict__ cw,
                                                        const float* __restrict__ cb,
                                                        float* __restrict__ xc,
                                                        unsigned short* __restrict__ xcb) {
  int g = blockIdx.x * 256 + threadIdx.x;  // 786432 groups exactly
  int c4 = (g % 384) * 4;
  int row = g / 384;
  int l = row & (LSEQ - 1);
  f32x4 acc = *(const f32x4*)(cb + c4);
  f32x4 w[4];
#pragma unroll
  for (int ci = 0; ci < 4; ci++) w[ci] = *(const f32x4*)(cw + (c4 + ci) * 4);
#pragma unroll
  for (int j = 0; j < 4; j++) {
    int dl = l - 3 + j;
    if (dl >= 0) {
      f32x4 xv = *(const f32x4*)(xz + (size_t)(row - 3 + j) * 3072 + c4);
#pragma unroll
      for (int ci = 0; ci < 4; ci++) acc[ci] = fmaf(xv[ci], w[ci][j], acc[ci]);
    }
  }
  f32x4 val;
  u16x4 ob;
#pragma unroll
  for (int ci = 0; ci < 4; ci++) {
    float sg = 1.0f / (1.0f + expf(-acc[ci]));
    val[ci] = acc[ci] * sg;
    ob[ci] = f2bu(val[ci]);
  }
  *(f32x4*)(xc + (size_t)row * D_INNER + c4) = val;
  *(u16x4*)(xcb + (size_t)row * D_INNER + c4) = ob;
}

// ---- per (b,l): dt transform, closed-form rank-1 NS gamma, u' = gamma*dt*x ----
// f32x4 everywhere: 384 groups of 4 channels over 2 unrolled passes.
__global__ __launch_bounds__(256) void precompute_kernel(const float* __restrict__ xdbl,
                                                         float* __restrict__ dtbuf,
                                                         const float* __restrict__ xconv,
                                                         const float* __restrict__ dtb,
                                                         float* __restrict__ ubuf,
                                                         float* __restrict__ kqbuf) {
  int row = blockIdx.x;
  int t = threadIdx.x;
  const float* xr = xdbl + (size_t)row * 80;
  float nk = 0.0f;
#pragma unroll
  for (int n = 0; n < 16; n++) { float kv = xr[48 + n]; nk += kv * kv; }
  f32x4 dtf[2], u0[2];
  float nupart = 0.0f;
#pragma unroll
  for (int gi = 0; gi < 2; gi++) {
    int g = gi * 256 + t;
    if (g < 384) {
      int d = g * 4;
      f32x4 draw = *(const f32x4*)(dtbuf + (size_t)row * D_INNER + d);
      f32x4 bb = *(const f32x4*)(dtb + d);
      f32x4 xcv = *(const f32x4*)(xconv + (size_t)row * D_INNER + d);
      f32x4 df, uu;
#pragma unroll
      for (int j = 0; j < 4; j++) {
        float sg = 1.0f / (1.0f + expf(-(draw[j] + bb[j])));
        float dv = sg / (1.0f + sg * nk);
        df[j] = dv;
        float u = dv * xcv[j];
        uu[j] = u;
        nupart += u * u;
      }
      dtf[gi] = df;
      u0[gi] = uu;
    }
  }
  __shared__ float red[4];
  float v = nupart;
#pragma unroll
  for (int off = 32; off > 0; off >>= 1) v += __shfl_xor(v, off);
  if ((t & 63) == 0) red[t >> 6] = v;
  __syncthreads();
  float nu = red[0] + red[1] + red[2] + red[3];
  float p = nu * nk;
  float s = sqrtf(p) + 1e-7f;
  float tt = p / (s * s);
  float gamma = (3.4445f + tt * (-4.7750f + 2.0315f * tt)) / s;
#pragma unroll
  for (int gi = 0; gi < 2; gi++) {
    int g = gi * 256 + t;
    if (g < 384) {
      int d = g * 4;
      f32x4 df = dtf[gi], uu = u0[gi], us;
#pragma unroll
      for (int j = 0; j < 4; j++) us[j] = gamma * uu[j];
      *(f32x4*)(dtbuf + (size_t)row * D_INNER + d) = df;
      *(f32x4*)(ubuf + (size_t)row * D_INNER + d) = us;
    }
  }
  if (t < 8)  // kq = xdbl[48:80) contiguous (k then q)
    *(f32x4*)(kqbuf + (size_t)row * 32 + t * 4) = *(const f32x4*)(xr + 48 + t * 4);
}

// ================= segmented scan =================
// 256-thread blocks: 64 d-channels x 4 n-groups. Prefetch: one f32x4 per array
// per thread (step = t>>4, colgroup = (t&15)*4) -> 16B/lane, 256B/step-row.
__global__ __launch_bounds__(256) void scan_phase1(const float* __restrict__ ubuf,
                                                   const float* __restrict__ dtbuf,
                                                   const float* __restrict__ kqbuf,
                                                   float* __restrict__ cvp,
                                                   float* __restrict__ chp,
                                                   float* __restrict__ gp,
                                                   float* __restrict__ rp) {
  __shared__ __align__(16) float u_s[2][STP][64];
  __shared__ __align__(16) float dt_s[2][STP][64];
  __shared__ __align__(16) float kq_s[2][STP][36];
  const int t = threadIdx.x;
  const int nq = t & 3, dloc = t >> 2;  // dloc 0..63
  const int b = blockIdx.x / (24 * CCH);
  const int rem = blockIdx.x % (24 * CCH);
  const int d0 = (rem / CCH) * 64;
  const int c = rem % CCH;
  const int tbase = c * CLEN;
  const size_t ub = (size_t)b * LSEQ * D_INNER + d0;
  const float* kqb = kqbuf + (size_t)b * LSEQ * 32;
  const int prow = t >> 4, pcol = (t & 15) * 4;  // 16 steps x 16 colgroups
  const int krow = t >> 3, kcol = (t & 7) * 4;   // t<128: 16 rows x 32 cols
  f32x4 pu, pd, pk;
  auto prefetch = [&](int t0) {
    size_t off = ub + (size_t)(t0 + prow) * D_INNER + pcol;
    pu = *(const f32x4*)(ubuf + off);
    pd = *(const f32x4*)(dtbuf + off);
    if (t < 128) pk = *(const f32x4*)(kqb + (size_t)(t0 + krow) * 32 + kcol);
  };
  auto writelds = [&](int bi) {
    *(f32x4*)&u_s[bi][prow][pcol] = pu;
    *(f32x4*)&dt_s[bi][prow][pcol] = pd;
    if (t < 128) *(f32x4*)&kq_s[bi][krow][kcol] = pk;
  };
  f32x4 v = {0.f, 0.f, 0.f, 0.f}, h = {0.f, 0.f, 0.f, 0.f};
  f32x4 g = {0.f, 0.f, 0.f, 0.f}, r = {1.f, 1.f, 1.f, 1.f};
  float bt = 0.9f;
  prefetch(tbase);
  writelds(0);
  __syncthreads();
  int buf = 0;
  for (int t0 = 0; t0 < CLEN; t0 += STP) {
    const bool more = (t0 + STP < CLEN);
    if (more) prefetch(tbase + t0 + STP);
#pragma unroll 4
    for (int s = 0; s < STP; s++) {
      float u = u_s[buf][s][dloc];
      float dtf = dt_s[buf][s][dloc];
      f32x4 kv = *(const f32x4*)&kq_s[buf][s][nq * 4];
#pragma unroll
      for (int j = 0; j < 4; j++) {
        float kj = kv[j];
        v[j] = fmaf(0.9f, v[j], u * kj);
        float a = fmaf(-dtf * kj, kj, 1.0f);
        h[j] = fmaf(a, h[j], v[j]);
        r[j] *= a;
        g[j] = fmaf(a, g[j], bt);
      }
      bt *= 0.9f;
    }
    if (more) writelds(buf ^ 1);  // writes buf^1: no conflict with readers of buf
    __syncthreads();              // publish buf^1 before next tile reads it
    buf ^= 1;
  }
  size_t o = (((size_t)b * CCH + c) * D_INNER + d0 + dloc) * 16 + nq * 4;
  *(f32x4*)(cvp + o) = v;
  *(f32x4*)(chp + o) = h;
  *(f32x4*)(gp + o) = g;
  *(f32x4*)(rp + o) = r;
}

__global__ __launch_bounds__(256) void scan_phase2(const float* __restrict__ cvp,
                                                   const float* __restrict__ chp,
                                                   float* __restrict__ gp,
                                                   float* __restrict__ rp) {
  int i4 = (blockIdx.x * 256 + threadIdx.x) * 4;  // 49152 elems = 48 blocks
  int b = i4 / (D_INNER * 16);
  int rem = i4 % (D_INNER * 16);
  f32x4 v0 = {0.f, 0.f, 0.f, 0.f}, h0 = {0.f, 0.f, 0.f, 0.f};
#pragma unroll
  for (int c = 0; c < CCH; c++) {
    size_t o = ((size_t)(b * CCH + c)) * (D_INNER * 16) + rem;
    f32x4 cv = *(const f32x4*)(cvp + o);
    f32x4 ch = *(const f32x4*)(chp + o);
    f32x4 gg = *(const f32x4*)(gp + o);
    f32x4 rr = *(const f32x4*)(rp + o);
    *(f32x4*)(gp + o) = v0;
    *(f32x4*)(rp + o) = h0;
#pragma unroll
    for (int j = 0; j < 4; j++) {
      float v0n = fmaf(BETA_CL, v0[j], cv[j]);
      float h0n = fmaf(gg[j], v0[j], fmaf(rr[j], h0[j], ch[j]));
      v0[j] = v0n;
      h0[j] = h0n;
    }
  }
}

// phase3 fuses the gate: ygb = bf16((y_scan + D*xconv) * silu(z))
__global__ __launch_bounds__(256) void scan_phase3(const float* __restrict__ ubuf,
                                                   const float* __restrict__ dtbuf,
                                                   const float* __restrict__ kqbuf,
                                                   const float* __restrict__ gp,
                                                   const float* __restrict__ rp,
                                                   const float* __restrict__ xconv,
                                                   const float* __restrict__ xz,
                                                   const float* __restrict__ Dp,
                                                   unsigned short* __restrict__ ygb) {
  __shared__ __align__(16) float u_s[2][STP][64];
  __shared__ __align__(16) float dt_s[2][STP][64];
  __shared__ __align__(16) float xc_s[2][STP][64];
  __shared__ __align__(16) float z_s[2][STP][64];
  __shared__ __align__(16) float kq_s[2][STP][36];
  const int t = threadIdx.x;
  const int nq = t & 3, dloc = t >> 2;
  const int b = blockIdx.x / (24 * CCH);
  const int rem = blockIdx.x % (24 * CCH);
  const int d0 = (rem / CCH) * 64;
  const int c = rem % CCH;
  const int tbase = c * CLEN;
  const size_t ub = (size_t)b * LSEQ * D_INNER + d0;
  const float* kqb = kqbuf + (size_t)b * LSEQ * 32;
  const float* xzb = xz + (size_t)b * LSEQ * 3072 + 1536 + d0;  // z half, col base d0
  unsigned short* y_p = ygb + (size_t)b * LSEQ * D_INNER + d0 + dloc;
  const int prow = t >> 4, pcol = (t & 15) * 4;
  const int krow = t >> 3, kcol = (t & 7) * 4;
  f32x4 pu, pd, pxc, pz, pk;
  auto prefetch = [&](int t0) {
    size_t off = ub + (size_t)(t0 + prow) * D_INNER + pcol;
    pu = *(const f32x4*)(ubuf + off);
    pd = *(const f32x4*)(dtbuf + off);
    pxc = *(const f32x4*)(xconv + off);
    pz = *(const f32x4*)(xzb + (size_t)(t0 + prow) * 3072 + pcol);
    if (t < 128) pk = *(const f32x4*)(kqb + (size_t)(t0 + krow) * 32 + kcol);
  };
  auto writelds = [&](int bi) {
    *(f32x4*)&u_s[bi][prow][pcol] = pu;
    *(f32x4*)&dt_s[bi][prow][pcol] = pd;
    *(f32x4*)&xc_s[bi][prow][pcol] = pxc;
    *(f32x4*)&z_s[bi][prow][pcol] = pz;
    if (t < 128) *(f32x4*)&kq_s[bi][krow][kcol] = pk;
  };
  size_t so = (((size_t)b * CCH + c) * D_INNER + d0 + dloc) * 16 + nq * 4;
  f32x4 v = *(const f32x4*)(gp + so);
  f32x4 h = *(const f32x4*)(rp + so);
  const float Dd = Dp[d0 + dloc];
  prefetch(tbase);
  writelds(0);
  __syncthreads();
  int buf = 0;
  for (int t0 = 0; t0 < CLEN; t0 += STP) {
    const bool more = (t0 + STP < CLEN);
    if (more) prefetch(tbase + t0 + STP);
#pragma unroll 4
    for (int s = 0; s < STP; s++) {
      float u = u_s[buf][s][dloc];
      float dtf = dt_s[buf][s][dloc];
      f32x4 kv = *(const f32x4*)&kq_s[buf][s][nq * 4];
      f32x4 qv = *(const f32x4*)&kq_s[buf][s][16 + nq * 4];
      float yp = 0.0f;
#pragma unroll
      for (int j = 0; j < 4; j++) {
        float kj = kv[j];
        v[j] = fmaf(0.9f, v[j], u * kj);
        float dA = fmaf(-dtf * kj, kj, 1.0f);
        h[j] = fmaf(dA, h[j], v[j]);
        yp = fmaf(h[j], qv[j], yp);
      }
      yp += __shfl_xor(yp, 1);
      yp += __shfl_xor(yp, 2);
      float zv = z_s[buf][s][dloc];
      float sz = zv / (1.0f + expf(-zv));
      float val = (yp + Dd * xc_s[buf][s][dloc]) * sz;
      if (nq == 0) y_p[(size_t)(tbase + t0 + s) * D_INNER] = f2bu(val);
    }
    if (more) writelds(buf ^ 1);
    __syncthreads();
    buf ^= 1;
  }
}

extern "C" void kernel_launch(void* const* d_in, const int* in_sizes, int n_in,
                              void* d_out, int out_size, void* d_ws, size_t ws_size,
                              hipStream_t stream) {
  const float* hidden = (const float*)d_in[0];
  const float* w_in   = (const float*)d_in[1];
  const float* conv_w = (const float*)d_in[2];
  const float* conv_b = (const float*)d_in[3];
  const float* w_x    = (const float*)d_in[4];
  const float* w_dt   = (const float*)d_in[5];
  const float* b_dt   = (const float*)d_in[6];
  const float* w_out  = (const float*)d_in[7];
  const float* Dp     = (const float*)d_in[8];

  float* ws    = (float*)d_ws;
  float* xz    = ws;                                  // 2048*3072
  float* xconv = xz + (size_t)NROWS * 3072;           // 2048*1536
  float* xdbl  = xconv + (size_t)NROWS * D_INNER;     // 2048*80
  float* dtbuf = xdbl + (size_t)NROWS * 80;           // 2048*1536
  float* ubuf  = dtbuf + (size_t)NROWS * D_INNER;     // 2048*1536
  float* kqbuf = ubuf + (size_t)NROWS * D_INNER;      // 2048*32
  const size_t PL = (size_t)NB * CCH * D_INNER * 16;  // 786432 per plane (CCH=16)
  float* cvp   = kqbuf + (size_t)NROWS * 32;
  float* chp   = cvp + PL;
  float* gp    = chp + PL;
  float* rp    = gp + PL;
  unsigned short* bfr = (unsigned short*)(rp + PL);
  unsigned short* hbf = bfr;                          // 1572864
  unsigned short* wib = hbf + 1572864;                // 2359296
  unsigned short* wxb = wib + 2359296;                // 122880
  unsigned short* wdb = wxb + 122880;                 // 73728
  unsigned short* wob = wdb + 73728;                  // 1179648
  unsigned short* xcb = wob + 1179648;                // 3145728
  unsigned short* ygb = xcb + 3145728;                // 3145728

  dim3 blk(256);
  // 0. cvt static operands to bf16 + zero xdbl/d_out/xz (split-K atomic targets)
  cvt5z_kernel<<<dim3((CVT_TOTAL + Z1_GROUPS + Z2_GROUPS + Z3_GROUPS) / 256), blk, 0, stream>>>(
      hidden, w_in, w_x, w_dt, w_out, hbf, wib, wxb, wdb, wob, xdbl, (float*)d_out, xz);
  // 1. in_proj: 128x128 split-K=2, atomic (2048 x 3072, K=768) -> 768 blocks = 3/CU
  gemm128<true><<<dim3(24, 16, 2), blk, 0, stream>>>(hbf, wib, xz, 768, 768, 768, 3072, 384);
  // 2. causal conv + SiLU (fp32 + bf16 outputs), 4 ch/thread
  conv_silu_kernel<<<dim3(3072), blk, 0, stream>>>(xz, conv_w, conv_b, xconv, xcb);
  // 3. x_proj: 64-tile split-K=8, atomic (2048 x 80, K=1536)
  gemm_bt<false, true><<<dim3(2, 32, 8), blk, 0, stream>>>(xcb, wxb, xdbl, 2048, 80, 1536,
                                                           1536, 1536, 80, 192);
  // 4. dt_head: 64-tile, fp32-A (2048 x 1536, K=48)
  gemm_bt<true, false><<<dim3(24, 32, 1), blk, 0, stream>>>(xdbl, wdb, dtbuf, 2048, 1536, 48,
                                                            80, 48, 1536, 48);
  // 5. precompute dt-final, gamma, u', k, q (vectorized)
  precompute_kernel<<<dim3(NROWS), blk, 0, stream>>>(xdbl, dtbuf, xconv, b_dt, ubuf, kqbuf);
  // 6. segmented scan: 3 phases (phase3 fuses the gate -> bf16 ygb)
  scan_phase1<<<dim3(NB * 24 * CCH), blk, 0, stream>>>(ubuf, dtbuf, kqbuf, cvp, chp, gp, rp);
  scan_phase2<<<dim3(48), blk, 0, stream>>>(cvp, chp, gp, rp);
  scan_phase3<<<dim3(NB * 24 * CCH), blk, 0, stream>>>(ubuf, dtbuf, kqbuf, gp, rp,
                                                       xconv, xz, Dp, ygb);
  // 7. out_proj: 128x128 split-K=8, atomic -> FP32 d_out (2048 x 768, K=1536) -> 768 blocks
  gemm128<true><<<dim3(6, 16, 8), blk, 0, stream>>>(ygb, wob, (float*)d_out, 1536,
                                                    1536, 1536, 768, 192);
}

// Round 5
// 203.444 us; speedup vs baseline: 1.2950x; 1.2950x over previous
//
#include <hip/hip_runtime.h>

#define D_MODEL 768
#define D_STATE 16
#define D_INNER 1536
#define DT_RANK 48
#define NB 2
#define LSEQ 1024
#define NROWS (NB * LSEQ)
#define CCH 16                 // chunks over L
#define CLEN (LSEQ / CCH)      // 64 steps per chunk
#define STP 16                 // steps staged per LDS tile
#define BETA_CL 1.1790185e-03f // 0.9^64
#define OUT_ELEMS (NROWS * D_MODEL)  // 1572864 fp32 out_proj outputs

typedef __attribute__((ext_vector_type(4))) float f32x4;
typedef __attribute__((ext_vector_type(8))) short s16x8;
typedef __attribute__((ext_vector_type(8))) unsigned short u16x8;
typedef __attribute__((ext_vector_type(4))) unsigned short u16x4;

__device__ __forceinline__ unsigned short f2bu(float f) {
  unsigned int x = __builtin_bit_cast(unsigned int, f);
  x += 0x7fffu + ((x >> 16) & 1u);
  return (unsigned short)(x >> 16);
}

// direct global->LDS async copy, 16B per lane. LDS dest is wave-uniform base +
// lane*16 (m104): pass the wave's segment base, lanes are implicit.
typedef __attribute__((address_space(3))) unsigned int as3u32;
typedef __attribute__((address_space(1))) const unsigned int as1u32;
__device__ __forceinline__ void gload16(const unsigned short* g, unsigned short* l) {
  __builtin_amdgcn_global_load_lds((as1u32*)g, (as3u32*)l, 16, 0, 0);
}

// ---- one-shot: cvt 5 static operands to bf16 + zero x_proj atomic target ----
// cvt segments (8-elem groups): hidden 196608 | w_in 294912 | w_x 15360 | w_dt 9216 | w_out 147456
#define CVT_TOTAL 663552
#define Z1_GROUPS 20480   // xdbl: 163840 floats
__global__ __launch_bounds__(256) void cvt5z_kernel(const float* __restrict__ s0,
                                                    const float* __restrict__ s1,
                                                    const float* __restrict__ s2,
                                                    const float* __restrict__ s3,
                                                    const float* __restrict__ s4,
                                                    unsigned short* __restrict__ d0,
                                                    unsigned short* __restrict__ d1,
                                                    unsigned short* __restrict__ d2,
                                                    unsigned short* __restrict__ d3,
                                                    unsigned short* __restrict__ d4,
                                                    float* __restrict__ z1) {
  int g = blockIdx.x * 256 + threadIdx.x;
  if (g >= CVT_TOTAL) {
    int zg = g - CVT_TOTAL;
    f32x4 zero = {0.f, 0.f, 0.f, 0.f};
    if (zg < Z1_GROUPS) {
      *(f32x4*)(z1 + zg * 8) = zero;
      *(f32x4*)(z1 + zg * 8 + 4) = zero;
    }
    return;
  }
  const float* s;
  unsigned short* d;
  int base;
  if (g < 196608)      { s = s0; d = d0; base = 0; }
  else if (g < 491520) { s = s1; d = d1; base = 196608; }
  else if (g < 506880) { s = s2; d = d2; base = 491520; }
  else if (g < 516096) { s = s3; d = d3; base = 506880; }
  else                 { s = s4; d = d4; base = 516096; }
  int i = (g - base) * 8;
  f32x4 a = *(const f32x4*)(s + i);
  f32x4 b = *(const f32x4*)(s + i + 4);
  u16x8 o;
#pragma unroll
  for (int j = 0; j < 4; j++) { o[j] = f2bu(a[j]); o[4 + j] = f2bu(b[j]); }
  *(u16x8*)(d + i) = o;
}

// ---- 128x128 GEMM, bf16 in, fp32 accum. REQUIRES M%128==0, N%128==0, kseg%32==0 ----
// 4 waves, each 64x64 (4x4 16x16 frags, 16 MFMA / K32-iter). Double-buffered LDS,
// staged via global_load_lds dwordx4 (m97 structure: linear [128][32], no pad).
// PARTIAL: split-K writes non-atomic partials to plane blockIdx.z (NO atomics —
// per-element fp32 atomicAdd measured ~970 GB/s RMW-bound, 51us epilogues in r4).
template <bool PARTIAL>
__global__ __launch_bounds__(256) void gemm128(const unsigned short* __restrict__ A,
                                               const unsigned short* __restrict__ B,
                                               float* __restrict__ C, int K,
                                               int lda, int ldb, int ldc, int kseg_len) {
  __shared__ __align__(16) unsigned short As[2][128 * 32];
  __shared__ __align__(16) unsigned short Bs[2][128 * 32];
  const int m0 = blockIdx.y * 128, n0 = blockIdx.x * 128;
  const int kbeg = blockIdx.z * kseg_len;
  const int kend = kbeg + kseg_len;
  const int t = threadIdx.x;
  const int wave = t >> 6, lane = t & 63;
  const int wm = wave >> 1, wn = wave & 1;
  const int quad = lane >> 4, l16 = lane & 15;
  const int srow = lane >> 2;       // row within a 16-row wave segment
  const int kcol = (lane & 3) * 8;  // bf16 elems within the 32-wide K slab

  float* Cp = C;
  if constexpr (PARTIAL) Cp = C + (size_t)blockIdx.z * (size_t)gridDim.y * 128 * ldc;

  auto stage = [&](int bi, int k0) {
#pragma unroll
    for (int r = 0; r < 2; r++) {
      const int seg = r * 64 + wave * 16;
      gload16(A + (size_t)(m0 + seg + srow) * lda + k0 + kcol, &As[bi][seg * 32]);
      gload16(B + (size_t)(n0 + seg + srow) * ldb + k0 + kcol, &Bs[bi][seg * 32]);
    }
  };

  f32x4 acc[4][4] = {};
  stage(0, kbeg);
  __syncthreads();
  int buf = 0;
  for (int k0 = kbeg; k0 < kend; k0 += 32) {
    if (k0 + 32 < kend) stage(buf ^ 1, k0 + 32);  // loads in flight during MFMA
    s16x8 af[4], bf[4];
#pragma unroll
    for (int i = 0; i < 4; i++) {
      af[i] = *(const s16x8*)&As[buf][(wm * 64 + i * 16 + l16) * 32 + quad * 8];
      bf[i] = *(const s16x8*)&Bs[buf][(wn * 64 + i * 16 + l16) * 32 + quad * 8];
    }
#pragma unroll
    for (int mi = 0; mi < 4; mi++)
#pragma unroll
      for (int ni = 0; ni < 4; ni++)
        acc[mi][ni] = __builtin_amdgcn_mfma_f32_16x16x32_bf16(af[mi], bf[ni], acc[mi][ni], 0, 0, 0);
    __syncthreads();
    buf ^= 1;
  }
#pragma unroll
  for (int mi = 0; mi < 4; mi++)
#pragma unroll
    for (int ni = 0; ni < 4; ni++)
#pragma unroll
      for (int r = 0; r < 4; r++) {
        int row = m0 + wm * 64 + mi * 16 + quad * 4 + r;
        int col = n0 + wn * 64 + ni * 16 + l16;
        Cp[(size_t)row * ldc + col] = acc[mi][ni][r];
      }
}

// ---- sum 4 split-K partial planes -> d_out ----
__global__ __launch_bounds__(256) void reduce4_kernel(const float* __restrict__ part,
                                                      float* __restrict__ out) {
  int i4 = (blockIdx.x * 256 + threadIdx.x) * 4;  // OUT_ELEMS/4 threads
  f32x4 a = *(const f32x4*)(part + i4);
  f32x4 b = *(const f32x4*)(part + (size_t)OUT_ELEMS + i4);
  f32x4 c = *(const f32x4*)(part + (size_t)2 * OUT_ELEMS + i4);
  f32x4 d = *(const f32x4*)(part + (size_t)3 * OUT_ELEMS + i4);
  f32x4 o;
#pragma unroll
  for (int j = 0; j < 4; j++) o[j] = (a[j] + b[j]) + (c[j] + d[j]);
  *(f32x4*)(out + i4) = o;
}

// ---- 64x64 GEMM (bounds-checked) for x_proj / dt_head ----
template <bool AF32, bool ATOMIC>
__global__ __launch_bounds__(256) void gemm_bt(const void* __restrict__ Av,
                                               const unsigned short* __restrict__ B,
                                               float* __restrict__ C, int M, int N, int K,
                                               int lda, int ldb, int ldc, int kseg_len) {
  __shared__ __align__(16) unsigned short As[2][64][40];
  __shared__ __align__(16) unsigned short Bs[2][64][40];
  const int m0 = blockIdx.y * 64, n0 = blockIdx.x * 64;
  const int kbeg = blockIdx.z * kseg_len;
  const int kend = (kbeg + kseg_len < K) ? (kbeg + kseg_len) : K;
  const int t = threadIdx.x;
  const int wave = t >> 6, lane = t & 63;
  const int wm = wave >> 1, wn = wave & 1;
  const int quad = lane >> 4, l16 = lane & 15;
  const int srow = t >> 2;
  const int kseg = (t & 3) * 8;
  const bool va = (m0 + srow) < M, vb = (n0 + srow) < N;
  const float* Af = (const float*)Av;
  const unsigned short* Ab = (const unsigned short*)Av;
  const unsigned short* Bp = B + (size_t)(n0 + srow) * ldb;

  f32x4 ra0, ra1;
  u16x8 rab, rbb;
  auto pref = [&](int k0) {
    const int kk = k0 + kseg;
    const int krem = kend - kk;
    if constexpr (AF32) {
      const float* Ap = Af + (size_t)(m0 + srow) * lda + kk;
      if (va && krem >= 8) {
        ra0 = *(const f32x4*)Ap;
        ra1 = *(const f32x4*)(Ap + 4);
      } else {
#pragma unroll
        for (int j = 0; j < 4; j++) {
          ra0[j] = (va && j < krem) ? Ap[j] : 0.0f;
          ra1[j] = (va && j + 4 < krem) ? Ap[j + 4] : 0.0f;
        }
      }
    } else {
      const unsigned short* Ap = Ab + (size_t)(m0 + srow) * lda + kk;
      if (va && krem >= 8) {
        rab = *(const u16x8*)Ap;
      } else {
#pragma unroll
        for (int j = 0; j < 8; j++) rab[j] = (va && j < krem) ? Ap[j] : (unsigned short)0;
      }
    }
    if (vb && krem >= 8) {
      rbb = *(const u16x8*)(Bp + kk);
    } else {
#pragma unroll
      for (int j = 0; j < 8; j++) rbb[j] = (vb && j < krem) ? Bp[kk + j] : (unsigned short)0;
    }
  };
  auto tolds = [&](int bi) {
    if constexpr (AF32) {
      u16x8 oa;
#pragma unroll
      for (int j = 0; j < 4; j++) { oa[j] = f2bu(ra0[j]); oa[4 + j] = f2bu(ra1[j]); }
      *(u16x8*)&As[bi][srow][kseg] = oa;
    } else {
      *(u16x8*)&As[bi][srow][kseg] = rab;
    }
    *(u16x8*)&Bs[bi][srow][kseg] = rbb;
  };

  f32x4 acc[2][2] = {};
  pref(kbeg);
  tolds(0);
  __syncthreads();
  int buf = 0;
  for (int k0 = kbeg; k0 < kend; k0 += 32) {
    const bool more = (k0 + 32 < kend);
    if (more) pref(k0 + 32);
    s16x8 a0 = *(const s16x8*)&As[buf][wm * 32 + l16][quad * 8];
    s16x8 a1 = *(const s16x8*)&As[buf][wm * 32 + 16 + l16][quad * 8];
    s16x8 b0 = *(const s16x8*)&Bs[buf][wn * 32 + l16][quad * 8];
    s16x8 b1 = *(const s16x8*)&Bs[buf][wn * 32 + 16 + l16][quad * 8];
    acc[0][0] = __builtin_amdgcn_mfma_f32_16x16x32_bf16(a0, b0, acc[0][0], 0, 0, 0);
    acc[0][1] = __builtin_amdgcn_mfma_f32_16x16x32_bf16(a0, b1, acc[0][1], 0, 0, 0);
    acc[1][0] = __builtin_amdgcn_mfma_f32_16x16x32_bf16(a1, b0, acc[1][0], 0, 0, 0);
    acc[1][1] = __builtin_amdgcn_mfma_f32_16x16x32_bf16(a1, b1, acc[1][1], 0, 0, 0);
    if (more) tolds(buf ^ 1);
    __syncthreads();
    buf ^= 1;
  }
#pragma unroll
  for (int mi = 0; mi < 2; mi++)
#pragma unroll
    for (int ni = 0; ni < 2; ni++)
#pragma unroll
      for (int r = 0; r < 4; r++) {
        int row = m0 + wm * 32 + mi * 16 + quad * 4 + r;
        int col = n0 + wn * 32 + ni * 16 + l16;
        if (row < M && col < N) {
          if constexpr (ATOMIC)
            atomicAdd(&C[(size_t)row * ldc + col], acc[mi][ni][r]);
          else
            C[(size_t)row * ldc + col] = acc[mi][ni][r];
        }
      }
}

// ---- causal depthwise conv (width 4) + SiLU; 4 channels/thread, 16B loads ----
__global__ __launch_bounds__(256) void conv_silu_kernel(const float* __restrict__ xz,
                                                        const float* __restrict__ cw,
                                                        const float* __restrict__ cb,
                                                        float* __restrict__ xc,
                                                        unsigned short* __restrict__ xcb) {
  int g = blockIdx.x * 256 + threadIdx.x;  // 786432 groups exactly
  int c4 = (g % 384) * 4;
  int row = g / 384;
  int l = row & (LSEQ - 1);
  f32x4 acc = *(const f32x4*)(cb + c4);
  f32x4 w[4];
#pragma unroll
  for (int ci = 0; ci < 4; ci++) w[ci] = *(const f32x4*)(cw + (c4 + ci) * 4);
#pragma unroll
  for (int j = 0; j < 4; j++) {
    int dl = l - 3 + j;
    if (dl >= 0) {
      f32x4 xv = *(const f32x4*)(xz + (size_t)(row - 3 + j) * 3072 + c4);
#pragma unroll
      for (int ci = 0; ci < 4; ci++) acc[ci] = fmaf(xv[ci], w[ci][j], acc[ci]);
    }
  }
  f32x4 val;
  u16x4 ob;
#pragma unroll
  for (int ci = 0; ci < 4; ci++) {
    float sg = 1.0f / (1.0f + expf(-acc[ci]));
    val[ci] = acc[ci] * sg;
    ob[ci] = f2bu(val[ci]);
  }
  *(f32x4*)(xc + (size_t)row * D_INNER + c4) = val;
  *(u16x4*)(xcb + (size_t)row * D_INNER + c4) = ob;
}

// ---- per (b,l): dt transform, closed-form rank-1 NS gamma, u' = gamma*dt*x ----
// f32x4 everywhere: 384 groups of 4 channels over 2 unrolled passes.
__global__ __launch_bounds__(256) void precompute_kernel(const float* __restrict__ xdbl,
                                                         float* __restrict__ dtbuf,
                                                         const float* __restrict__ xconv,
                                                         const float* __restrict__ dtb,
                                                         float* __restrict__ ubuf,
                                                         float* __restrict__ kqbuf) {
  int row = blockIdx.x;
  int t = threadIdx.x;
  const float* xr = xdbl + (size_t)row * 80;
  float nk = 0.0f;
#pragma unroll
  for (int n = 0; n < 16; n++) { float kv = xr[48 + n]; nk += kv * kv; }
  f32x4 dtf[2], u0[2];
  float nupart = 0.0f;
#pragma unroll
  for (int gi = 0; gi < 2; gi++) {
    int g = gi * 256 + t;
    if (g < 384) {
      int d = g * 4;
      f32x4 draw = *(const f32x4*)(dtbuf + (size_t)row * D_INNER + d);
      f32x4 bb = *(const f32x4*)(dtb + d);
      f32x4 xcv = *(const f32x4*)(xconv + (size_t)row * D_INNER + d);
      f32x4 df, uu;
#pragma unroll
      for (int j = 0; j < 4; j++) {
        float sg = 1.0f / (1.0f + expf(-(draw[j] + bb[j])));
        float dv = sg / (1.0f + sg * nk);
        df[j] = dv;
        float u = dv * xcv[j];
        uu[j] = u;
        nupart += u * u;
      }
      dtf[gi] = df;
      u0[gi] = uu;
    }
  }
  __shared__ float red[4];
  float v = nupart;
#pragma unroll
  for (int off = 32; off > 0; off >>= 1) v += __shfl_xor(v, off);
  if ((t & 63) == 0) red[t >> 6] = v;
  __syncthreads();
  float nu = red[0] + red[1] + red[2] + red[3];
  float p = nu * nk;
  float s = sqrtf(p) + 1e-7f;
  float tt = p / (s * s);
  float gamma = (3.4445f + tt * (-4.7750f + 2.0315f * tt)) / s;
#pragma unroll
  for (int gi = 0; gi < 2; gi++) {
    int g = gi * 256 + t;
    if (g < 384) {
      int d = g * 4;
      f32x4 df = dtf[gi], uu = u0[gi], us;
#pragma unroll
      for (int j = 0; j < 4; j++) us[j] = gamma * uu[j];
      *(f32x4*)(dtbuf + (size_t)row * D_INNER + d) = df;
      *(f32x4*)(ubuf + (size_t)row * D_INNER + d) = us;
    }
  }
  if (t < 8)  // kq = xdbl[48:80) contiguous (k then q)
    *(f32x4*)(kqbuf + (size_t)row * 32 + t * 4) = *(const f32x4*)(xr + 48 + t * 4);
}

// ================= segmented scan =================
// 256-thread blocks: 64 d-channels x 4 n-groups. Prefetch: one f32x4 per array
// per thread (step = t>>4, colgroup = (t&15)*4) -> 16B/lane, 256B/step-row.
__global__ __launch_bounds__(256) void scan_phase1(const float* __restrict__ ubuf,
                                                   const float* __restrict__ dtbuf,
                                                   const float* __restrict__ kqbuf,
                                                   float* __restrict__ cvp,
                                                   float* __restrict__ chp,
                                                   float* __restrict__ gp,
                                                   float* __restrict__ rp) {
  __shared__ __align__(16) float u_s[2][STP][64];
  __shared__ __align__(16) float dt_s[2][STP][64];
  __shared__ __align__(16) float kq_s[2][STP][36];
  const int t = threadIdx.x;
  const int nq = t & 3, dloc = t >> 2;  // dloc 0..63
  const int b = blockIdx.x / (24 * CCH);
  const int rem = blockIdx.x % (24 * CCH);
  const int d0 = (rem / CCH) * 64;
  const int c = rem % CCH;
  const int tbase = c * CLEN;
  const size_t ub = (size_t)b * LSEQ * D_INNER + d0;
  const float* kqb = kqbuf + (size_t)b * LSEQ * 32;
  const int prow = t >> 4, pcol = (t & 15) * 4;  // 16 steps x 16 colgroups
  const int krow = t >> 3, kcol = (t & 7) * 4;   // t<128: 16 rows x 32 cols
  f32x4 pu, pd, pk;
  auto prefetch = [&](int t0) {
    size_t off = ub + (size_t)(t0 + prow) * D_INNER + pcol;
    pu = *(const f32x4*)(ubuf + off);
    pd = *(const f32x4*)(dtbuf + off);
    if (t < 128) pk = *(const f32x4*)(kqb + (size_t)(t0 + krow) * 32 + kcol);
  };
  auto writelds = [&](int bi) {
    *(f32x4*)&u_s[bi][prow][pcol] = pu;
    *(f32x4*)&dt_s[bi][prow][pcol] = pd;
    if (t < 128) *(f32x4*)&kq_s[bi][krow][kcol] = pk;
  };
  f32x4 v = {0.f, 0.f, 0.f, 0.f}, h = {0.f, 0.f, 0.f, 0.f};
  f32x4 g = {0.f, 0.f, 0.f, 0.f}, r = {1.f, 1.f, 1.f, 1.f};
  float bt = 0.9f;
  prefetch(tbase);
  writelds(0);
  __syncthreads();
  int buf = 0;
  for (int t0 = 0; t0 < CLEN; t0 += STP) {
    const bool more = (t0 + STP < CLEN);
    if (more) prefetch(tbase + t0 + STP);
#pragma unroll 4
    for (int s = 0; s < STP; s++) {
      float u = u_s[buf][s][dloc];
      float dtf = dt_s[buf][s][dloc];
      f32x4 kv = *(const f32x4*)&kq_s[buf][s][nq * 4];
#pragma unroll
      for (int j = 0; j < 4; j++) {
        float kj = kv[j];
        v[j] = fmaf(0.9f, v[j], u * kj);
        float a = fmaf(-dtf * kj, kj, 1.0f);
        h[j] = fmaf(a, h[j], v[j]);
        r[j] *= a;
        g[j] = fmaf(a, g[j], bt);
      }
      bt *= 0.9f;
    }
    if (more) writelds(buf ^ 1);  // writes buf^1: no conflict with readers of buf
    __syncthreads();              // publish buf^1 before next tile reads it
    buf ^= 1;
  }
  size_t o = (((size_t)b * CCH + c) * D_INNER + d0 + dloc) * 16 + nq * 4;
  *(f32x4*)(cvp + o) = v;
  *(f32x4*)(chp + o) = h;
  *(f32x4*)(gp + o) = g;
  *(f32x4*)(rp + o) = r;
}

__global__ __launch_bounds__(256) void scan_phase2(const float* __restrict__ cvp,
                                                   const float* __restrict__ chp,
                                                   float* __restrict__ gp,
                                                   float* __restrict__ rp) {
  int i4 = (blockIdx.x * 256 + threadIdx.x) * 4;  // 49152 elems = 48 blocks
  int b = i4 / (D_INNER * 16);
  int rem = i4 % (D_INNER * 16);
  f32x4 v0 = {0.f, 0.f, 0.f, 0.f}, h0 = {0.f, 0.f, 0.f, 0.f};
#pragma unroll
  for (int c = 0; c < CCH; c++) {
    size_t o = ((size_t)(b * CCH + c)) * (D_INNER * 16) + rem;
    f32x4 cv = *(const f32x4*)(cvp + o);
    f32x4 ch = *(const f32x4*)(chp + o);
    f32x4 gg = *(const f32x4*)(gp + o);
    f32x4 rr = *(const f32x4*)(rp + o);
    *(f32x4*)(gp + o) = v0;
    *(f32x4*)(rp + o) = h0;
#pragma unroll
    for (int j = 0; j < 4; j++) {
      float v0n = fmaf(BETA_CL, v0[j], cv[j]);
      float h0n = fmaf(gg[j], v0[j], fmaf(rr[j], h0[j], ch[j]));
      v0[j] = v0n;
      h0[j] = h0n;
    }
  }
}

// phase3 fuses the gate: ygb = bf16((y_scan + D*xconv) * silu(z))
__global__ __launch_bounds__(256) void scan_phase3(const float* __restrict__ ubuf,
                                                   const float* __restrict__ dtbuf,
                                                   const float* __restrict__ kqbuf,
                                                   const float* __restrict__ gp,
                                                   const float* __restrict__ rp,
                                                   const float* __restrict__ xconv,
                                                   const float* __restrict__ xz,
                                                   const float* __restrict__ Dp,
                                                   unsigned short* __restrict__ ygb) {
  __shared__ __align__(16) float u_s[2][STP][64];
  __shared__ __align__(16) float dt_s[2][STP][64];
  __shared__ __align__(16) float xc_s[2][STP][64];
  __shared__ __align__(16) float z_s[2][STP][64];
  __shared__ __align__(16) float kq_s[2][STP][36];
  const int t = threadIdx.x;
  const int nq = t & 3, dloc = t >> 2;
  const int b = blockIdx.x / (24 * CCH);
  const int rem = blockIdx.x % (24 * CCH);
  const int d0 = (rem / CCH) * 64;
  const int c = rem % CCH;
  const int tbase = c * CLEN;
  const size_t ub = (size_t)b * LSEQ * D_INNER + d0;
  const float* kqb = kqbuf + (size_t)b * LSEQ * 32;
  const float* xzb = xz + (size_t)b * LSEQ * 3072 + 1536 + d0;  // z half, col base d0
  unsigned short* y_p = ygb + (size_t)b * LSEQ * D_INNER + d0 + dloc;
  const int prow = t >> 4, pcol = (t & 15) * 4;
  const int krow = t >> 3, kcol = (t & 7) * 4;
  f32x4 pu, pd, pxc, pz, pk;
  auto prefetch = [&](int t0) {
    size_t off = ub + (size_t)(t0 + prow) * D_INNER + pcol;
    pu = *(const f32x4*)(ubuf + off);
    pd = *(const f32x4*)(dtbuf + off);
    pxc = *(const f32x4*)(xconv + off);
    pz = *(const f32x4*)(xzb + (size_t)(t0 + prow) * 3072 + pcol);
    if (t < 128) pk = *(const f32x4*)(kqb + (size_t)(t0 + krow) * 32 + kcol);
  };
  auto writelds = [&](int bi) {
    *(f32x4*)&u_s[bi][prow][pcol] = pu;
    *(f32x4*)&dt_s[bi][prow][pcol] = pd;
    *(f32x4*)&xc_s[bi][prow][pcol] = pxc;
    *(f32x4*)&z_s[bi][prow][pcol] = pz;
    if (t < 128) *(f32x4*)&kq_s[bi][krow][kcol] = pk;
  };
  size_t so = (((size_t)b * CCH + c) * D_INNER + d0 + dloc) * 16 + nq * 4;
  f32x4 v = *(const f32x4*)(gp + so);
  f32x4 h = *(const f32x4*)(rp + so);
  const float Dd = Dp[d0 + dloc];
  prefetch(tbase);
  writelds(0);
  __syncthreads();
  int buf = 0;
  for (int t0 = 0; t0 < CLEN; t0 += STP) {
    const bool more = (t0 + STP < CLEN);
    if (more) prefetch(tbase + t0 + STP);
#pragma unroll 4
    for (int s = 0; s < STP; s++) {
      float u = u_s[buf][s][dloc];
      float dtf = dt_s[buf][s][dloc];
      f32x4 kv = *(const f32x4*)&kq_s[buf][s][nq * 4];
      f32x4 qv = *(const f32x4*)&kq_s[buf][s][16 + nq * 4];
      float yp = 0.0f;
#pragma unroll
      for (int j = 0; j < 4; j++) {
        float kj = kv[j];
        v[j] = fmaf(0.9f, v[j], u * kj);
        float dA = fmaf(-dtf * kj, kj, 1.0f);
        h[j] = fmaf(dA, h[j], v[j]);
        yp = fmaf(h[j], qv[j], yp);
      }
      yp += __shfl_xor(yp, 1);
      yp += __shfl_xor(yp, 2);
      float zv = z_s[buf][s][dloc];
      float sz = zv / (1.0f + expf(-zv));
      float val = (yp + Dd * xc_s[buf][s][dloc]) * sz;
      if (nq == 0) y_p[(size_t)(tbase + t0 + s) * D_INNER] = f2bu(val);
    }
    if (more) writelds(buf ^ 1);
    __syncthreads();
    buf ^= 1;
  }
}

extern "C" void kernel_launch(void* const* d_in, const int* in_sizes, int n_in,
                              void* d_out, int out_size, void* d_ws, size_t ws_size,
                              hipStream_t stream) {
  const float* hidden = (const float*)d_in[0];
  const float* w_in   = (const float*)d_in[1];
  const float* conv_w = (const float*)d_in[2];
  const float* conv_b = (const float*)d_in[3];
  const float* w_x    = (const float*)d_in[4];
  const float* w_dt   = (const float*)d_in[5];
  const float* b_dt   = (const float*)d_in[6];
  const float* w_out  = (const float*)d_in[7];
  const float* Dp     = (const float*)d_in[8];

  float* ws    = (float*)d_ws;
  float* xz    = ws;                                  // 2048*3072
  float* xconv = xz + (size_t)NROWS * 3072;           // 2048*1536
  float* xdbl  = xconv + (size_t)NROWS * D_INNER;     // 2048*80
  float* dtbuf = xdbl + (size_t)NROWS * 80;           // 2048*1536
  float* ubuf  = dtbuf + (size_t)NROWS * D_INNER;     // 2048*1536
  float* kqbuf = ubuf + (size_t)NROWS * D_INNER;      // 2048*32
  const size_t PL = (size_t)NB * CCH * D_INNER * 16;  // 786432 per plane (CCH=16)
  float* cvp   = kqbuf + (size_t)NROWS * 32;
  float* chp   = cvp + PL;
  float* gp    = chp + PL;
  float* rp    = gp + PL;
  float* opart = rp + PL;                             // 4 * OUT_ELEMS split-K partials
  unsigned short* bfr = (unsigned short*)(opart + (size_t)4 * OUT_ELEMS);
  unsigned short* hbf = bfr;                          // 1572864
  unsigned short* wib = hbf + 1572864;                // 2359296
  unsigned short* wxb = wib + 2359296;                // 122880
  unsigned short* wdb = wxb + 122880;                 // 73728
  unsigned short* wob = wdb + 73728;                  // 1179648
  unsigned short* xcb = wob + 1179648;                // 3145728
  unsigned short* ygb = xcb + 3145728;                // 3145728

  dim3 blk(256);
  // 0. cvt static operands to bf16 + zero xdbl (x_proj atomic target)
  cvt5z_kernel<<<dim3((CVT_TOTAL + Z1_GROUPS) / 256), blk, 0, stream>>>(
      hidden, w_in, w_x, w_dt, w_out, hbf, wib, wxb, wdb, wob, xdbl);
  // 1. in_proj: 128x128 tile, non-atomic (2048 x 3072, K=768)
  gemm128<false><<<dim3(24, 16, 1), blk, 0, stream>>>(hbf, wib, xz, 768, 768, 768, 3072, 768);
  // 2. causal conv + SiLU (fp32 + bf16 outputs), 4 ch/thread
  conv_silu_kernel<<<dim3(3072), blk, 0, stream>>>(xz, conv_w, conv_b, xconv, xcb);
  // 3. x_proj: 64-tile split-K=8, atomic (2048 x 80, K=1536; target 640KB, L2-resident)
  gemm_bt<false, true><<<dim3(2, 32, 8), blk, 0, stream>>>(xcb, wxb, xdbl, 2048, 80, 1536,
                                                           1536, 1536, 80, 192);
  // 4. dt_head: 64-tile, fp32-A (2048 x 1536, K=48)
  gemm_bt<true, false><<<dim3(24, 32, 1), blk, 0, stream>>>(xdbl, wdb, dtbuf, 2048, 1536, 48,
                                                            80, 48, 1536, 48);
  // 5. precompute dt-final, gamma, u', k, q (vectorized)
  precompute_kernel<<<dim3(NROWS), blk, 0, stream>>>(xdbl, dtbuf, xconv, b_dt, ubuf, kqbuf);
  // 6. segmented scan: 3 phases (phase3 fuses the gate -> bf16 ygb)
  scan_phase1<<<dim3(NB * 24 * CCH), blk, 0, stream>>>(ubuf, dtbuf, kqbuf, cvp, chp, gp, rp);
  scan_phase2<<<dim3(48), blk, 0, stream>>>(cvp, chp, gp, rp);
  scan_phase3<<<dim3(NB * 24 * CCH), blk, 0, stream>>>(ubuf, dtbuf, kqbuf, gp, rp,
                                                       xconv, xz, Dp, ygb);
  // 7. out_proj: 128x128 split-K=4 -> non-atomic partial planes (2048 x 768, K=1536)
  gemm128<true><<<dim3(6, 16, 4), blk, 0, stream>>>(ygb, wob, opart, 1536,
                                                    1536, 1536, 768, 384);
  // 8. reduce 4 partial planes -> d_out
  reduce4_kernel<<<dim3(OUT_ELEMS / 1024), blk, 0, stream>>>(opart, (float*)d_out);
}